// Round 2
// baseline (161.102 us; speedup 1.0000x reference)
//
#include <hip/hip_runtime.h>
#include <hip/hip_bf16.h>

typedef float f32x4 __attribute__((ext_vector_type(4)));
typedef short s16x8 __attribute__((ext_vector_type(8)));

#define SIGC 2379
#define KPAD 2432
#define NPATH 12800

__device__ inline void split2(float v, __hip_bfloat16* h, __hip_bfloat16* l) {
    __hip_bfloat16 hh = __float2bfloat16(v);
    *h = hh;
    *l = __float2bfloat16(v - __bfloat162float(hh));
}

// ---------------------------------------------------------------------------
// W convert: W[256][2379] fp32 -> Wh/Wl[256][2432] bf16 hi+lo (pad zeroed)
// ---------------------------------------------------------------------------
__global__ __launch_bounds__(256) void wconv_kernel(const float* __restrict__ W,
                                                    __hip_bfloat16* __restrict__ Wh,
                                                    __hip_bfloat16* __restrict__ Wl)
{
    int k = blockIdx.x * 256 + threadIdx.x;
    int n = blockIdx.y;
    if (k < KPAD) {
        float v = (k < SIGC) ? W[(size_t)n * SIGC + k] : 0.0f;
        split2(v, &Wh[(size_t)n * KPAD + k], &Wl[(size_t)n * KPAD + k]);
    }
}

// ---------------------------------------------------------------------------
// Signature kernel: one wave per path (4 paths/wave, 16/block).
// Register-only scan: lane owns pairs p in {lane, lane+64, lane+128(<169)},
// tracks s1[i], s2[p] in registers; only inc table is in LDS (write-once).
// s3[ijk] += dx[k] * (s2[ij] + 0.5*dx[j]*(s1[i] + dx[i]/3))
// ---------------------------------------------------------------------------
__global__ __launch_bounds__(256) void sig_kernel(const float* __restrict__ x,
                                                  __hip_bfloat16* __restrict__ Ah,
                                                  __hip_bfloat16* __restrict__ Al_,
                                                  int r_start)
{
    __shared__ float inc_s[4][5][16];   // [wave][step][channel]

    const int t = threadIdx.x;
    const int w = t >> 6;
    const int lane = t & 63;

    const int p0 = lane;
    const int p1 = lane + 64;
    const int p2 = lane + 128;
    const bool has2 = (p2 < 169);
    const int i0 = p0 / 13, j0 = p0 - i0 * 13;
    const int i1 = p1 / 13, j1 = p1 - i1 * 13;
    const int i2 = p2 / 13, j2 = p2 - i2 * 13;   // only used under has2

    for (int pp = 0; pp < 4; ++pp) {
        const int r = r_start + blockIdx.x * 16 + w * 4 + pp;
        const int nn = r & 7;
        const int jj = (r >> 3) & 63;
        const int ii = r >> 9;

        __syncthreads();   // protect inc_s reuse across pp iterations
        if (lane < 13) {
            if (lane < 12) {
                const float* px = x + ((size_t)(nn * 12 + lane) * 1600 + ii * 64 + jj) * 5;
                float prev = 0.0f;
                #pragma unroll
                for (int l = 0; l < 5; ++l) {
                    float v = px[l];
                    inc_s[w][l][lane] = v - prev;
                    prev = v;
                }
            } else {
                inc_s[w][0][12] = 0.0f;
                #pragma unroll
                for (int l = 1; l < 5; ++l) inc_s[w][l][12] = 0.25f;
            }
        }
        __syncthreads();

        float s1i0 = 0.0f, s1i1 = 0.0f, s1i2 = 0.0f;
        float s2p0 = 0.0f, s2p1 = 0.0f, s2p2 = 0.0f;
        float s1own = 0.0f;
        float s3a[13], s3b[13], s3c[13];
        #pragma unroll
        for (int k = 0; k < 13; ++k) { s3a[k] = 0.0f; s3b[k] = 0.0f; s3c[k] = 0.0f; }

        for (int l = 0; l < 5; ++l) {
            float dxl[13];
            #pragma unroll
            for (int k = 0; k < 13; ++k) dxl[k] = inc_s[w][l][k];

            // pair 0
            {
                float dxi = inc_s[w][l][i0];
                float dxj = inc_s[w][l][j0];
                float C   = s2p0 + 0.5f * dxj * (s1i0 + dxi * (1.0f / 3.0f));
                #pragma unroll
                for (int k = 0; k < 13; ++k) s3a[k] += dxl[k] * C;
                s2p0 += s1i0 * dxj + 0.5f * dxi * dxj;
                s1i0 += dxi;
            }
            // pair 1
            {
                float dxi = inc_s[w][l][i1];
                float dxj = inc_s[w][l][j1];
                float C   = s2p1 + 0.5f * dxj * (s1i1 + dxi * (1.0f / 3.0f));
                #pragma unroll
                for (int k = 0; k < 13; ++k) s3b[k] += dxl[k] * C;
                s2p1 += s1i1 * dxj + 0.5f * dxi * dxj;
                s1i1 += dxi;
            }
            // pair 2 (lanes with p2 < 169 only)
            if (has2) {
                float dxi = inc_s[w][l][i2];
                float dxj = inc_s[w][l][j2];
                float C   = s2p2 + 0.5f * dxj * (s1i2 + dxi * (1.0f / 3.0f));
                #pragma unroll
                for (int k = 0; k < 13; ++k) s3c[k] += dxl[k] * C;
                s2p2 += s1i2 * dxj + 0.5f * dxi * dxj;
                s1i2 += dxi;
            }
            // running s1 for write-out (channel = lane)
            if (lane < 13) s1own += inc_s[w][l][lane];
        }

        // ---- write hi/lo bf16 sig row: [s1(13) | s2(169) | s3(2197) | pad] ----
        __hip_bfloat16* AhR = Ah + (size_t)(r - r_start) * KPAD;
        __hip_bfloat16* AlR = Al_ + (size_t)(r - r_start) * KPAD;
        if (lane < 13) split2(s1own, &AhR[lane], &AlR[lane]);
        split2(s2p0, &AhR[13 + p0], &AlR[13 + p0]);
        split2(s2p1, &AhR[13 + p1], &AlR[13 + p1]);
        if (has2) split2(s2p2, &AhR[13 + p2], &AlR[13 + p2]);
        #pragma unroll
        for (int k = 0; k < 13; ++k) split2(s3a[k], &AhR[182 + p0 * 13 + k], &AlR[182 + p0 * 13 + k]);
        #pragma unroll
        for (int k = 0; k < 13; ++k) split2(s3b[k], &AhR[182 + p1 * 13 + k], &AlR[182 + p1 * 13 + k]);
        if (has2) {
            #pragma unroll
            for (int k = 0; k < 13; ++k) split2(s3c[k], &AhR[182 + p2 * 13 + k], &AlR[182 + p2 * 13 + k]);
        }
        if (lane < KPAD - SIGC) {
            AhR[SIGC + lane] = __float2bfloat16(0.0f);
            AlR[SIGC + lane] = __float2bfloat16(0.0f);
        }
    }
}

// ---------------------------------------------------------------------------
// Split-bf16 GEMM: D[m][o] = sum_k A[m][k]*W[o][k], A ~ Ah+Al, W ~ Wh+Wl.
// acc += Ah*Wh + Ah*Wl + Al*Wh  (al*wl dropped, ~1e-5 rel).
// 128x128 block tile, 4 waves 2x2, each wave 4x4 frags of 16x16x32 bf16.
// Epilogue adds bias and scatters to out[n][o][i][j].
// ---------------------------------------------------------------------------
__global__ __launch_bounds__(256) void gemm_kernel(const __hip_bfloat16* __restrict__ Ah,
                                                   const __hip_bfloat16* __restrict__ Al_,
                                                   const __hip_bfloat16* __restrict__ Wh,
                                                   const __hip_bfloat16* __restrict__ Wl,
                                                   const float* __restrict__ bias,
                                                   float* __restrict__ out,
                                                   int r_start)
{
    __shared__ __hip_bfloat16 LAh[128 * 40];   // 32 bf16 + 8 pad per row (80 B)
    __shared__ __hip_bfloat16 LAl[128 * 40];
    __shared__ __hip_bfloat16 LBh[128 * 40];
    __shared__ __hip_bfloat16 LBl[128 * 40];

    const int t = threadIdx.x;
    const int lane = t & 63;
    const int w = t >> 6;
    const int wm = w >> 1, wn = w & 1;
    const int m0 = blockIdx.y * 128;
    const int n0 = blockIdx.x * 128;

    f32x4 acc[4][4] = {};

    for (int k0 = 0; k0 < KPAD; k0 += 32) {
        __syncthreads();
        #pragma unroll
        for (int cc = 0; cc < 2; ++cc) {
            int c2 = t + 256 * cc;
            int row = c2 >> 2;
            int kseg = c2 & 3;
            size_t ga = (size_t)(m0 + row) * KPAD + k0 + kseg * 8;
            size_t gb = (size_t)(n0 + row) * KPAD + k0 + kseg * 8;
            int lo = row * 40 + kseg * 8;
            *reinterpret_cast<int4*>(&LAh[lo]) = *reinterpret_cast<const int4*>(Ah + ga);
            *reinterpret_cast<int4*>(&LAl[lo]) = *reinterpret_cast<const int4*>(Al_ + ga);
            *reinterpret_cast<int4*>(&LBh[lo]) = *reinterpret_cast<const int4*>(Wh + gb);
            *reinterpret_cast<int4*>(&LBl[lo]) = *reinterpret_cast<const int4*>(Wl + gb);
        }
        __syncthreads();

        s16x8 ah[4], al4[4], bh[4], bl4[4];
        #pragma unroll
        for (int m = 0; m < 4; ++m) {
            int lo = (wm * 64 + m * 16 + (lane & 15)) * 40 + (lane >> 4) * 8;
            ah[m]  = *reinterpret_cast<const s16x8*>(&LAh[lo]);
            al4[m] = *reinterpret_cast<const s16x8*>(&LAl[lo]);
        }
        #pragma unroll
        for (int n = 0; n < 4; ++n) {
            int lo = (wn * 64 + n * 16 + (lane & 15)) * 40 + (lane >> 4) * 8;
            bh[n]  = *reinterpret_cast<const s16x8*>(&LBh[lo]);
            bl4[n] = *reinterpret_cast<const s16x8*>(&LBl[lo]);
        }

        #pragma unroll
        for (int m = 0; m < 4; ++m)
            #pragma unroll
            for (int n = 0; n < 4; ++n) {
                acc[m][n] = __builtin_amdgcn_mfma_f32_16x16x32_bf16(ah[m],  bh[n],  acc[m][n], 0, 0, 0);
                acc[m][n] = __builtin_amdgcn_mfma_f32_16x16x32_bf16(ah[m],  bl4[n], acc[m][n], 0, 0, 0);
                acc[m][n] = __builtin_amdgcn_mfma_f32_16x16x32_bf16(al4[m], bh[n],  acc[m][n], 0, 0, 0);
            }
    }

    // epilogue: bias + scatter (C/D layout: col=lane&15, row=(lane>>4)*4+reg)
    #pragma unroll
    for (int m = 0; m < 4; ++m) {
        int prow_base = m0 + wm * 64 + m * 16 + ((lane >> 4) << 2);
        #pragma unroll
        for (int n = 0; n < 4; ++n) {
            int o = n0 + wn * 64 + n * 16 + (lane & 15);
            float bo = bias[o];
            #pragma unroll
            for (int rr = 0; rr < 4; ++rr) {
                int path = r_start + prow_base + rr;
                int ni = path & 7;
                int jj = (path >> 3) & 63;
                int ii = path >> 9;
                out[(size_t)(ni * 256 + o) * 1600 + ii * 64 + jj] = acc[m][n][rr] + bo;
            }
        }
    }
}

// ---------------------------------------------------------------------------
extern "C" void kernel_launch(void* const* d_in, const int* in_sizes, int n_in,
                              void* d_out, int out_size, void* d_ws, size_t ws_size,
                              hipStream_t stream)
{
    const float* x = (const float*)d_in[0];
    const float* W = (const float*)d_in[1];
    const float* b = (const float*)d_in[2];
    float* out = (float*)d_out;

    char* ws = (char*)d_ws;
    __hip_bfloat16* Wh = (__hip_bfloat16*)ws;
    __hip_bfloat16* Wl = Wh + (size_t)256 * KPAD;
    size_t a_off = (((size_t)256 * KPAD * 2 * 2) + 255) & ~(size_t)255;

    size_t avail = (ws_size > a_off) ? ws_size - a_off : 0;
    long long maxp = (long long)(avail / ((size_t)KPAD * 2 * 2));
    int chunk = (int)((maxp / 128) * 128);
    if (chunk > NPATH) chunk = NPATH;
    if (chunk < 128) chunk = 128;   // assume ws is at least ~4 MB

    __hip_bfloat16* Ah = (__hip_bfloat16*)(ws + a_off);
    __hip_bfloat16* Al_ = Ah + (size_t)chunk * KPAD;

    wconv_kernel<<<dim3(10, 256), 256, 0, stream>>>(W, Wh, Wl);

    for (int r0 = 0; r0 < NPATH; r0 += chunk) {
        int cnt = NPATH - r0;
        if (cnt > chunk) cnt = chunk;
        sig_kernel<<<dim3(cnt / 16), 256, 0, stream>>>(x, Ah, Al_, r0);
        gemm_kernel<<<dim3(2, cnt / 128), 256, 0, stream>>>(Ah, Al_, Wh, Wl, b, out, r0);
    }
}